// Round 5
// baseline (586.086 us; speedup 1.0000x reference)
//
#include <hip/hip_runtime.h>

typedef unsigned short u16;
typedef unsigned int u32;
typedef __bf16 bf16x8 __attribute__((ext_vector_type(8)));
typedef float f32x4 __attribute__((ext_vector_type(4)));

#define S_LEN 2048
#define NH 16
#define HD 128

#define AS1 __attribute__((address_space(1)))
#define AS3 __attribute__((address_space(3)))

__device__ __forceinline__ u16 f2bf(float x) {
  u32 u = __builtin_bit_cast(u32, x);
  u32 r = u + 0x7FFFu + ((u >> 16) & 1u);  // RNE
  return (u16)(r >> 16);
}
__device__ __forceinline__ float bf2f(u16 b) {
  return __builtin_bit_cast(float, (u32)b << 16);
}

// ---------------- fp32 -> bf16 conversion (vectorized, G13) ----------------
__global__ void cvt_f32_bf16(const float* __restrict__ in, u16* __restrict__ out, int n4) {
  int i = blockIdx.x * 256 + threadIdx.x;
  if (i >= n4) return;
  float4 v = ((const float4*)in)[i];
  ushort4 o;
  o.x = f2bf(v.x); o.y = f2bf(v.y); o.z = f2bf(v.z); o.w = f2bf(v.w);
  ((ushort4*)out)[i] = o;
}

// ---------------- RoPE cos/sin table: tab[0..S*64) = cos, [S*64..) = sin ----
__global__ void build_tab(float* __restrict__ tab) {
  int t = blockIdx.x * 256 + threadIdx.x;
  int s = t >> 6, j = t & 63;
  float inv = exp2f(-(float)j * 0.20762050593045083f);
  float ang = (float)s * inv;
  tab[t] = cosf(ang);
  tab[131072 + t] = sinf(ang);
}

// ---------------- GEMM: C[M,N] = A[M,K]*B[N,K]^T -----------------------------
// 256x256 tile, BK=32, 8 waves (2x4). A: LDS ring-4 via global_load_lds
// (distance-2 prefetch, boundary vmcnt(2), never drained). B: reg-staged,
// double-buffered in named frag sets (global->VGPR, no LDS). m201 phase
// micro-order: read -> barrier -> lgkm(0) -> setprio MFMA -> barrier.
__device__ __forceinline__ void storeC(u16* p, float v) { *p = f2bf(v); }
__device__ __forceinline__ void storeC(float* p, float v) { *p = v; }

template <typename OutT>
__global__ __launch_bounds__(512, 2) void gemm_bt3(const u16* __restrict__ A, const u16* __restrict__ B,
                                                   OutT* __restrict__ C, int M, int N, int K, int nbx) {
  __shared__ alignas(16) u16 As[32768];  // 4 bufs x 16KB (A only)
  char* lds = (char*)As;
  const int tid = threadIdx.x;
  const int lane = tid & 63;
  const int w = tid >> 6;              // 0..7
  const int wr = w >> 2, wc = w & 3;   // 2 x 4 wave grid
  const int g = lane >> 4, c = lane & 15;

  // XCD-aware bijective swizzle (nwg multiple of 8)
  const int nwg = gridDim.x;
  const int id = blockIdx.x;
  const int sw = (id & 7) * (nwg >> 3) + (id >> 3);
  const int bx = sw % nbx, by = sw / nbx;
  const size_t rowBase = (size_t)by * 256;
  const size_t colBase = (size_t)bx * 256;

  const char* Ap = (const char*)(A + rowBase * (size_t)K);
  const u16* Bsrc = B + (colBase + (size_t)(wc * 64 + c)) * (size_t)K + g * 8;

  // A staging: thread covers 2 x 16B per K-tile; LDS [256 rows][4 x 16B chunk],
  // chunk permuted by T(row) = (row ^ (row>>2)) & 3 (involution); gload_lds
  // writes linearly -> inverse-permute the per-lane global SOURCE.
  int dstOff[2], srcO[2];
#pragma unroll
  for (int s = 0; s < 2; ++s) {
    int base = (w * 2 + s) * 1024;
    dstOff[s] = base;
    int L = base + lane * 16;
    int row = L >> 6;
    int pc = (L >> 4) & 3;
    int T = (row ^ (row >> 2)) & 3;
    srcO[s] = row * (K * 2) + ((pc ^ T) << 4);
  }
  int aoff[8];
#pragma unroll
  for (int m = 0; m < 8; ++m) {
    int row = wr * 128 + m * 16 + c;
    int T = (row ^ (row >> 2)) & 3;
    aoff[m] = row * 64 + ((g ^ T) << 4);
  }

  f32x4 acc[8][4];
#pragma unroll
  for (int m = 0; m < 8; ++m)
#pragma unroll
    for (int n = 0; n < 4; ++n) acc[m][n] = f32x4{0.f, 0.f, 0.f, 0.f};

  const int NT = K >> 5;

  auto stageA = [&](int tt, int s) {
    __builtin_amdgcn_global_load_lds((const AS1 void*)(Ap + srcO[s] + tt * 64),
                                     (AS3 void*)(lds + (tt & 3) * 16384 + dstOff[s]), 16, 0, 0);
  };
  auto loadB = [&](bf16x8 (&bq)[4], int tt) {
#pragma unroll
    for (int n = 0; n < 4; ++n)
      bq[n] = *(const bf16x8*)(Bsrc + (size_t)n * 16 * K + tt * 32);
  };

  bf16x8 bqA[4], bqB[4];
  // prologue: issue order = [bq(0) x4, gA(0) x2, gA(1) x2] -> vmcnt(2)
  loadB(bqA, 0);
  __builtin_amdgcn_sched_barrier(0);
  stageA(0, 0); stageA(0, 1);
  stageA(1, 0); stageA(1, 1);
  asm volatile("s_waitcnt vmcnt(2)" ::: "memory");
  __builtin_amdgcn_s_barrier();

  auto tileBody = [&](int t, bf16x8 (&bcur)[4], bf16x8 (&bnxt)[4]) {
    const char* bufA = lds + (t & 3) * 16384;
    // issue next-tile B first (keeps vmcnt(2) math: newest 2 = gA(t+2))
    if (t + 1 < NT) loadB(bnxt, t + 1);
    __builtin_amdgcn_sched_barrier(0);
    bf16x8 aF[4];
    // ---- phase A: m0-3
#pragma unroll
    for (int m = 0; m < 4; ++m) aF[m] = *(const bf16x8*)(bufA + aoff[m]);
    if (t + 2 < NT) stageA(t + 2, 0);
    __builtin_amdgcn_s_barrier();
    asm volatile("s_waitcnt lgkmcnt(0)" ::: "memory");
    __builtin_amdgcn_sched_barrier(0);
    __builtin_amdgcn_s_setprio(1);
#pragma unroll
    for (int m = 0; m < 4; ++m)
#pragma unroll
      for (int n = 0; n < 4; ++n)
        acc[m][n] = __builtin_amdgcn_mfma_f32_16x16x32_bf16(aF[m], bcur[n], acc[m][n], 0, 0, 0);
    __builtin_amdgcn_s_setprio(0);
    __builtin_amdgcn_sched_barrier(0);
    __builtin_amdgcn_s_barrier();
    // ---- phase B: m4-7
#pragma unroll
    for (int m = 0; m < 4; ++m) aF[m] = *(const bf16x8*)(bufA + aoff[4 + m]);
    if (t + 2 < NT) stageA(t + 2, 1);
    __builtin_amdgcn_s_barrier();
    asm volatile("s_waitcnt lgkmcnt(0)" ::: "memory");
    __builtin_amdgcn_sched_barrier(0);
    __builtin_amdgcn_s_setprio(1);
#pragma unroll
    for (int m = 0; m < 4; ++m)
#pragma unroll
      for (int n = 0; n < 4; ++n)
        acc[4 + m][n] = __builtin_amdgcn_mfma_f32_16x16x32_bf16(aF[m], bcur[n], acc[4 + m][n], 0, 0, 0);
    __builtin_amdgcn_s_setprio(0);
    __builtin_amdgcn_sched_barrier(0);
    // ---- tile boundary: counted wait (B(t+1)+A(t+1) landed, gA(t+2) in flight)
    if (t + 2 < NT)      { asm volatile("s_waitcnt vmcnt(2)" ::: "memory"); }
    else if (t + 1 < NT) { asm volatile("s_waitcnt vmcnt(0)" ::: "memory"); }
    __builtin_amdgcn_s_barrier();
  };

#pragma unroll 1
  for (int t = 0; t < NT; t += 2) {
    tileBody(t, bqA, bqB);
    tileBody(t + 1, bqB, bqA);
  }

  // epilogue
#pragma unroll
  for (int m = 0; m < 8; ++m)
#pragma unroll
    for (int n = 0; n < 4; ++n) {
      size_t row = rowBase + wr * 128 + m * 16 + g * 4;
      size_t col = colBase + wc * 64 + n * 16 + c;
#pragma unroll
      for (int r = 0; r < 4; ++r)
        storeC(&C[(row + r) * (size_t)N + col], acc[m][n][r]);
    }
}

// ---------------- RoPE on q,k; writes Q,K in [B,H,S,HD] --------------------
__global__ void rope_qk(const u16* __restrict__ qkv, const float* __restrict__ tab,
                        u16* __restrict__ Q, u16* __restrict__ K) {
  int idx = blockIdx.x * 256 + threadIdx.x;
  int j = idx & 63;
  int s = (idx >> 6) & (S_LEN - 1);
  int h = (idx >> 17) & (NH - 1);
  int b = idx >> 21;
  float cs = tab[s * 64 + j];
  float sn = tab[131072 + s * 64 + j];
  size_t qbase = (((size_t)(b * S_LEN + s) * 3 + 0) * NH + h) * HD;
  size_t kbase = qbase + (size_t)NH * HD;
  size_t o = ((size_t)(b * NH + h) * S_LEN + s) * HD;
  float q1 = bf2f(qkv[qbase + j]),  q2 = bf2f(qkv[qbase + j + 64]);
  Q[o + j]      = f2bf(q1 * cs - q2 * sn);
  Q[o + j + 64] = f2bf(q2 * cs + q1 * sn);
  float k1 = bf2f(qkv[kbase + j]), k2 = bf2f(qkv[kbase + j + 64]);
  K[o + j]      = f2bf(k1 * cs - k2 * sn);
  K[o + j + 64] = f2bf(k2 * cs + k1 * sn);
}

// ---------------- V transpose: qkv v-slot -> Vt [B,H,HD,S] -----------------
__global__ void v_transpose(const u16* __restrict__ qkv, u16* __restrict__ Vt) {
  __shared__ u16 t[32][33];
  int bh = blockIdx.z;
  int s0 = blockIdx.x * 32;
  int d0 = blockIdx.y * 32;
  int b = bh >> 4, h = bh & 15;
  int col = threadIdx.x & 31;
  int row = threadIdx.x >> 5;
#pragma unroll
  for (int i = 0; i < 4; ++i) {
    int s = row + i * 8;
    t[s][col] = qkv[(((size_t)(b * S_LEN + s0 + s) * 3 + 2) * NH + h) * HD + d0 + col];
  }
  __syncthreads();
  size_t vb = ((size_t)bh * HD + d0) * S_LEN + s0;
#pragma unroll
  for (int i = 0; i < 4; ++i) {
    int d = row + i * 8;
    Vt[vb + (size_t)d * S_LEN + col] = t[col][d];
  }
}

// ---------------- causal flash attention: 8-wave block, LDS-staged K/V -----
__global__ __launch_bounds__(512, 4) void attn_fwd(const u16* __restrict__ Q, const u16* __restrict__ K,
                                                   const u16* __restrict__ Vt, u16* __restrict__ O) {
  __shared__ alignas(16) u16 Ks[2 * 64 * 128];
  __shared__ alignas(16) u16 Vs[2 * 128 * 64];
  __shared__ alignas(16) u16 Pl[8 * 16 * 64];
  const int tid = threadIdx.x;
  const int lane = tid & 63;
  const int w = tid >> 6;
  const int g = lane >> 4, c = lane & 15;
  const int bh = blockIdx.x;
  const int pair = blockIdx.y;
  const int b = bh >> 4, h = bh & 15;

  const u16* Qb = Q + (size_t)bh * S_LEN * HD;
  const u16* Kb = K + (size_t)bh * S_LEN * HD;
  const u16* Vb = Vt + (size_t)bh * HD * S_LEN;
  const float SL = 0.12751753f;
  const int swz = (c & 7) << 4;

  int ldsOff[2], srcK[2], srcV[2];
#pragma unroll
  for (int ii = 0; ii < 2; ++ii) {
    int p = (w * 2 + ii) * 1024 + lane * 16;
    ldsOff[ii] = p;
    int rk = p >> 8, ik = p & 255;
    srcK[ii] = rk * 256 + (ik ^ ((rk & 7) << 4));
    int rv = p >> 7, iv = p & 127;
    srcV[ii] = rv * (S_LEN * 2) + (iv ^ ((rv & 7) << 4));
  }
  int koff[4], voff[2];
#pragma unroll
  for (int kb = 0; kb < 4; ++kb) koff[kb] = (kb * 64 + g * 16) ^ swz;
  voff[0] = (g * 16) ^ swz;
  voff[1] = (64 + g * 16) ^ swz;
  int poff[4];
#pragma unroll
  for (int t = 0; t < 4; ++t) poff[t] = (t * 32 + g * 8) ^ swz;
  char* Pw = (char*)Pl + w * 2048;

#pragma unroll 1
  for (int ph = 0; ph < 2; ++ph) {
    const int sti = ph ? (15 - pair) : pair;
    const int qb0 = sti * 128;
    const int q0 = qb0 + w * 16;

    bf16x8 qf[4];
#pragma unroll
    for (int kb = 0; kb < 4; ++kb)
      qf[kb] = *(const bf16x8*)&Qb[(size_t)(q0 + c) * HD + kb * 32 + g * 8];

    f32x4 acc[8];
#pragma unroll
    for (int cb = 0; cb < 8; ++cb) acc[cb] = f32x4{0.f, 0.f, 0.f, 0.f};
    float m_i = -3e38f, l_i = 0.f;

    const int nsteps = sti * 2 + 2;
#pragma unroll
    for (int ii = 0; ii < 2; ++ii) {
      __builtin_amdgcn_global_load_lds((const AS1 void*)((const char*)Kb + srcK[ii]),
                                       (AS3 void*)((char*)Ks + ldsOff[ii] - lane * 16), 16, 0, 0);
      __builtin_amdgcn_global_load_lds((const AS1 void*)((const char*)Vb + srcV[ii]),
                                       (AS3 void*)((char*)Vs + ldsOff[ii] - lane * 16), 16, 0, 0);
    }
    __syncthreads();
    int cur = 0;

#pragma unroll 1
    for (int st = 0; st < nsteps; ++st) {
      const int kv0 = st << 6;
      if (st + 1 < nsteps) {
        const char* kbase = (const char*)Kb + (size_t)(kv0 + 64) * 256;
        const char* vbase = (const char*)Vb + (size_t)(kv0 + 64) * 2;
        const int nb = (cur ^ 1) * 16384;
#pragma unroll
        for (int ii = 0; ii < 2; ++ii) {
          __builtin_amdgcn_global_load_lds((const AS1 void*)(kbase + srcK[ii]),
                                           (AS3 void*)((char*)Ks + nb + ldsOff[ii] - lane * 16), 16, 0, 0);
          __builtin_amdgcn_global_load_lds((const AS1 void*)(vbase + srcV[ii]),
                                           (AS3 void*)((char*)Vs + nb + ldsOff[ii] - lane * 16), 16, 0, 0);
        }
      }
      if (kv0 < q0 + 16) {
        const char* Kt = (const char*)Ks + cur * 16384;
        const char* Vtl = (const char*)Vs + cur * 16384;
        f32x4 s[4];
#pragma unroll
        for (int t = 0; t < 4; ++t) s[t] = f32x4{0.f, 0.f, 0.f, 0.f};
#pragma unroll
        for (int t = 0; t < 4; ++t)
#pragma unroll
          for (int kb = 0; kb < 4; ++kb) {
            bf16x8 kf = *(const bf16x8*)(Kt + t * 4096 + c * 256 + koff[kb]);
            s[t] = __builtin_amdgcn_mfma_f32_16x16x32_bf16(kf, qf[kb], s[t], 0, 0, 0);
          }
        if (kv0 + 63 > q0) {
          const int lim = q0 + c - kv0 - 4 * g;
#pragma unroll
          for (int t = 0; t < 4; ++t)
#pragma unroll
            for (int r = 0; r < 4; ++r)
              s[t][r] = (16 * t + r <= lim) ? s[t][r] : -3e38f;
        }
        float mx = s[0][0];
#pragma unroll
        for (int t = 0; t < 4; ++t)
#pragma unroll
          for (int r = 0; r < 4; ++r) mx = fmaxf(mx, s[t][r]);
        mx = fmaxf(mx, __shfl_xor(mx, 16));
        mx = fmaxf(mx, __shfl_xor(mx, 32));
        const float mn = fmaxf(m_i, mx);
        const float alpha = exp2f((m_i - mn) * SL);
        float rs = 0.f;
#pragma unroll
        for (int t = 0; t < 4; ++t) {
          float p0 = exp2f((s[t][0] - mn) * SL);
          float p1 = exp2f((s[t][1] - mn) * SL);
          float p2 = exp2f((s[t][2] - mn) * SL);
          float p3 = exp2f((s[t][3] - mn) * SL);
          rs += (p0 + p1) + (p2 + p3);
          ushort4 pw;
          pw.x = f2bf(p0); pw.y = f2bf(p1); pw.z = f2bf(p2); pw.w = f2bf(p3);
          *(ushort4*)(Pw + c * 128 + poff[t]) = pw;
        }
        rs += __shfl_xor(rs, 16);
        rs += __shfl_xor(rs, 32);
        l_i = l_i * alpha + rs;
        m_i = mn;
        float ar[4];
#pragma unroll
        for (int r = 0; r < 4; ++r) ar[r] = __shfl(alpha, 4 * g + r);
#pragma unroll
        for (int cb = 0; cb < 8; ++cb)
#pragma unroll
          for (int r = 0; r < 4; ++r) acc[cb][r] *= ar[r];
        bf16x8 pa0 = *(const bf16x8*)(Pw + c * 128 + voff[0]);
        bf16x8 pa1 = *(const bf16x8*)(Pw + c * 128 + voff[1]);
#pragma unroll
        for (int cb = 0; cb < 8; ++cb) {
          bf16x8 vf0 = *(const bf16x8*)(Vtl + cb * 2048 + c * 128 + voff[0]);
          acc[cb] = __builtin_amdgcn_mfma_f32_16x16x32_bf16(pa0, vf0, acc[cb], 0, 0, 0);
          bf16x8 vf1 = *(const bf16x8*)(Vtl + cb * 2048 + c * 128 + voff[1]);
          acc[cb] = __builtin_amdgcn_mfma_f32_16x16x32_bf16(pa1, vf1, acc[cb], 0, 0, 0);
        }
      }
      __syncthreads();
      cur ^= 1;
    }
    float linv = 1.0f / l_i;
    float lr[4];
#pragma unroll
    for (int r = 0; r < 4; ++r) lr[r] = __shfl(linv, 4 * g + r);
#pragma unroll
    for (int cb = 0; cb < 8; ++cb)
#pragma unroll
      for (int r = 0; r < 4; ++r) {
        int q = q0 + 4 * g + r;
        O[(((size_t)b * S_LEN + q) * NH + h) * HD + cb * 16 + c] = f2bf(acc[cb][r] * lr[r]);
      }
  }
}

// ---------------------------------------------------------------------------
extern "C" void kernel_launch(void* const* d_in, const int* in_sizes, int n_in,
                              void* d_out, int out_size, void* d_ws, size_t ws_size,
                              hipStream_t stream) {
  const float* x    = (const float*)d_in[0];
  const float* wqkv = (const float*)d_in[1];
  const float* wo   = (const float*)d_in[2];
  float* out = (float*)d_out;
  char* ws = (char*)d_ws;

  u16*  xb    = (u16*)(ws + 0);            // reused as attn out later
  u16*  wqkvb = (u16*)(ws + 33554432);
  float* tab  = (float*)(ws + 58720256);   // unioned with wob (tab dead after rope)
  u16*  wob   = (u16*)(ws + 58720256);
  u16*  qkvb  = (u16*)(ws + 67108864);
  u16*  Vt    = (u16*)(ws + 167772160);
  u16*  attn  = (u16*)(ws + 0);
  u16*  Qr = (u16*)d_out;                  // d_out scratch: dead before GEMM2
  u16*  Kr = (u16*)d_out + 16777216;

  cvt_f32_bf16<<<16384, 256, 0, stream>>>(x, xb, 16777216 / 4);
  cvt_f32_bf16<<<12288, 256, 0, stream>>>(wqkv, wqkvb, 12582912 / 4);
  build_tab<<<512, 256, 0, stream>>>(tab);

  // qkv = x @ wqkv^T : M=8192, N=6144, K=2048 -> 24x32 = 768 blocks
  gemm_bt3<u16><<<768, 512, 0, stream>>>(xb, wqkvb, qkvb, 8192, 6144, 2048, 24);

  rope_qk<<<32768, 256, 0, stream>>>(qkvb, tab, Qr, Kr);
  v_transpose<<<dim3(64, 4, 64), 256, 0, stream>>>(qkvb, Vt);

  cvt_f32_bf16<<<4096, 256, 0, stream>>>(wo, wob, 4194304 / 4);

  attn_fwd<<<dim3(64, 8), 512, 0, stream>>>(Qr, Kr, Vt, attn);

  // out = attn @ wo^T : M=8192, N=2048, K=2048 -> 8x32 = 256 blocks
  gemm_bt3<float><<<256, 512, 0, stream>>>(attn, wob, out, 8192, 2048, 2048, 8);
}

// Round 6
// 465.617 us; speedup vs baseline: 1.2587x; 1.2587x over previous
//
#include <hip/hip_runtime.h>

typedef unsigned short u16;
typedef unsigned int u32;
typedef __bf16 bf16x8 __attribute__((ext_vector_type(8)));
typedef float f32x4 __attribute__((ext_vector_type(4)));

#define S_LEN 2048
#define NH 16
#define HD 128

#define AS1 __attribute__((address_space(1)))
#define AS3 __attribute__((address_space(3)))

__device__ __forceinline__ u16 f2bf(float x) {
  u32 u = __builtin_bit_cast(u32, x);
  u32 r = u + 0x7FFFu + ((u >> 16) & 1u);  // RNE
  return (u16)(r >> 16);
}
__device__ __forceinline__ float bf2f(u16 b) {
  return __builtin_bit_cast(float, (u32)b << 16);
}

// ---------------- fp32 -> bf16 conversion (vectorized, G13) ----------------
__global__ void cvt_f32_bf16(const float* __restrict__ in, u16* __restrict__ out, int n4) {
  int i = blockIdx.x * 256 + threadIdx.x;
  if (i >= n4) return;
  float4 v = ((const float4*)in)[i];
  ushort4 o;
  o.x = f2bf(v.x); o.y = f2bf(v.y); o.z = f2bf(v.z); o.w = f2bf(v.w);
  ((ushort4*)out)[i] = o;
}

// ---------------- RoPE cos/sin table ----------------------------------------
__global__ void build_tab(float* __restrict__ tab) {
  int t = blockIdx.x * 256 + threadIdx.x;
  int s = t >> 6, j = t & 63;
  float inv = exp2f(-(float)j * 0.20762050593045083f);
  float ang = (float)s * inv;
  tab[t] = cosf(ang);
  tab[131072 + t] = sinf(ang);
}

// ---------------- GEMM: C[M,N] = A[M,K]*B[N,K]^T (m201-port) ----------------
// 256x256 tile, BK=64, 8 waves (2x4). LDS 128KiB: A/B x dbuf2 x half2 x
// [128 rows][128B], st_16x32 swizzle (byte ^= ((byte>>9)&1)<<5), staged via
// inverse-swizzled global source + linear gload_lds dest. 4 phases/K-tile,
// 16 MFMA each; read-order-proven distance-2 staging; boundary vmcnt(7).
__device__ __forceinline__ void storeC(u16* p, float v) { *p = f2bf(v); }
__device__ __forceinline__ void storeC(float* p, float v) { *p = v; }

template <typename OutT>
__global__ __launch_bounds__(512, 2) void gemm_bt4(const u16* __restrict__ A, const u16* __restrict__ B,
                                                   OutT* __restrict__ C, int M, int N, int K, int nbx) {
  __shared__ alignas(16) u16 LDS[65536];  // 128 KiB
  char* lds = (char*)LDS;
  const int tid = threadIdx.x;
  const int lane = tid & 63;
  const int w = tid >> 6;              // 0..7
  const int wr = w >> 2, wc = w & 3;   // 2 x 4 wave grid
  const int g = lane >> 4, c = lane & 15;

  // XCD-aware bijective swizzle (nwg multiple of 8)
  const int nwg = gridDim.x;
  const int id = blockIdx.x;
  const int sw = (id & 7) * (nwg >> 3) + (id >> 3);
  const int bx = sw % nbx, by = sw / nbx;
  const size_t rowBase = (size_t)by * 256;
  const size_t colBase = (size_t)bx * 256;

  const int half = w & 1;              // which 128-row half this wave stages
  const int sub = (w >> 1) & 3;        // 0..3
  const size_t ldb = (size_t)K * 2;    // row stride in bytes
  // per-lane source decomposition for one gload instr (1KB = 8 rows x 128B):
  const int srow = lane >> 3;                                   // row within 8-row unit
  const int soff = (16 * (lane & 7)) ^ ((lane & 32) ? 32 : 0);  // inverse st_16x32
  const char* ApS = (const char*)A + (rowBase + half * 128 + srow) * ldb + soff;
  const char* BpS = (const char*)B + (colBase + half * 128 + srow) * ldb + soff;

  auto stA = [&](int u, int blk) {  // stage A rows [blk*32+sub*8, +8) of half, tile u
    const int r0 = blk * 32 + sub * 8;
    const int dst = ((u & 1) * 2 + half) * 16384 + r0 * 128;
    __builtin_amdgcn_global_load_lds((const AS1 void*)(ApS + (size_t)r0 * ldb + (size_t)u * 128),
                                     (AS3 void*)(lds + dst), 16, 0, 0);
  };
  auto stB = [&](int u, int jj) {   // stage B rows [ (sub*4+jj)*8, +8) of half, tile u
    const int r0 = (sub * 4 + jj) * 8;
    const int dst = 65536 + ((u & 1) * 2 + half) * 16384 + r0 * 128;
    __builtin_amdgcn_global_load_lds((const AS1 void*)(BpS + (size_t)r0 * ldb + (size_t)u * 128),
                                     (AS3 void*)(lds + dst), 16, 0, 0);
  };

  const int x4 = (c & 4) << 3;  // read-side st_16x32 term (row_l&4 == c&4)
  auto rdA = [&](int bA, int mi, int kk) -> bf16x8 {
    return *(const bf16x8*)(lds + bA + mi * 2048 + c * 128 + ((kk * 64 + g * 16) ^ x4));
  };
  auto rdB = [&](int bB, int n, int kk) -> bf16x8 {
    return *(const bf16x8*)(lds + bB + n * 2048 + c * 128 + ((kk * 64 + g * 16) ^ x4));
  };

  f32x4 acc[8][4];
#pragma unroll
  for (int m = 0; m < 8; ++m)
#pragma unroll
    for (int n = 0; n < 4; ++n) acc[m][n] = f32x4{0.f, 0.f, 0.f, 0.f};

  bf16x8 bf_[4][2];
  auto mfmaPair = [&](int mi, bf16x8 ak0, bf16x8 ak1) {
#pragma unroll
    for (int n = 0; n < 4; ++n) {
      acc[mi][n] = __builtin_amdgcn_mfma_f32_16x16x32_bf16(ak0, bf_[n][0], acc[mi][n], 0, 0, 0);
      acc[mi][n] = __builtin_amdgcn_mfma_f32_16x16x32_bf16(ak1, bf_[n][1], acc[mi][n], 0, 0, 0);
    }
  };

  const int NT = K >> 6;  // BK=64

  // prologue: fully stage tiles 0 and 1 (16 instr), wait tile 0 (8 left in flight)
#pragma unroll
  for (int b = 0; b < 4; ++b) stA(0, b);
#pragma unroll
  for (int j = 0; j < 4; ++j) stB(0, j);
#pragma unroll
  for (int b = 0; b < 4; ++b) stA(1, b);
#pragma unroll
  for (int j = 0; j < 4; ++j) stB(1, j);
  asm volatile("s_waitcnt vmcnt(8)" ::: "memory");
  __builtin_amdgcn_s_barrier();

#pragma unroll 1
  for (int t = 0; t < NT; ++t) {
    const int bA = (t & 1) * 32768 + wr * 16384;
    const int bB = 65536 + (t & 1) * 32768 + (wc >> 1) * 16384 + (wc & 1) * 8192;
    bf16x8 a00, a01, a10, a11;
    // ---- phase 1: A m0,m1 (4 reads) + all B (8 reads); stage blk3 of t+1
    a00 = rdA(bA, 0, 0); a01 = rdA(bA, 0, 1); a10 = rdA(bA, 1, 0); a11 = rdA(bA, 1, 1);
#pragma unroll
    for (int n = 0; n < 4; ++n) { bf_[n][0] = rdB(bB, n, 0); bf_[n][1] = rdB(bB, n, 1); }
    if (t >= 1 && t + 1 < NT) stA(t + 1, 3);  // blk3(t): read in ph4 of t-1 (done)
    __builtin_amdgcn_s_barrier();
    asm volatile("s_waitcnt lgkmcnt(0)" ::: "memory");
    __builtin_amdgcn_sched_barrier(0);
    __builtin_amdgcn_s_setprio(1);
    mfmaPair(0, a00, a01);
    mfmaPair(1, a10, a11);
    __builtin_amdgcn_s_setprio(0);
    __builtin_amdgcn_sched_barrier(0);
    __builtin_amdgcn_s_barrier();
    // ---- phase 2: A m2,m3; stage A-blk0(t+2) + B 2 units (blk0(t) read done in ph1)
    a00 = rdA(bA, 2, 0); a01 = rdA(bA, 2, 1); a10 = rdA(bA, 3, 0); a11 = rdA(bA, 3, 1);
    if (t + 2 < NT) { stA(t + 2, 0); stB(t + 2, 0); stB(t + 2, 1); }
    __builtin_amdgcn_s_barrier();
    asm volatile("s_waitcnt lgkmcnt(0)" ::: "memory");
    __builtin_amdgcn_sched_barrier(0);
    __builtin_amdgcn_s_setprio(1);
    mfmaPair(2, a00, a01);
    mfmaPair(3, a10, a11);
    __builtin_amdgcn_s_setprio(0);
    __builtin_amdgcn_sched_barrier(0);
    __builtin_amdgcn_s_barrier();
    // ---- phase 3: A m4,m5; stage A-blk1(t+2) + B 2 units
    a00 = rdA(bA, 4, 0); a01 = rdA(bA, 4, 1); a10 = rdA(bA, 5, 0); a11 = rdA(bA, 5, 1);
    if (t + 2 < NT) { stA(t + 2, 1); stB(t + 2, 2); stB(t + 2, 3); }
    __builtin_amdgcn_s_barrier();
    asm volatile("s_waitcnt lgkmcnt(0)" ::: "memory");
    __builtin_amdgcn_sched_barrier(0);
    __builtin_amdgcn_s_setprio(1);
    mfmaPair(4, a00, a01);
    mfmaPair(5, a10, a11);
    __builtin_amdgcn_s_setprio(0);
    __builtin_amdgcn_sched_barrier(0);
    __builtin_amdgcn_s_barrier();
    // ---- phase 4: A m6,m7; stage A-blk2(t+2); boundary counted vmcnt
    a00 = rdA(bA, 6, 0); a01 = rdA(bA, 6, 1); a10 = rdA(bA, 7, 0); a11 = rdA(bA, 7, 1);
    if (t + 2 < NT) stA(t + 2, 2);
    __builtin_amdgcn_s_barrier();
    asm volatile("s_waitcnt lgkmcnt(0)" ::: "memory");
    __builtin_amdgcn_sched_barrier(0);
    __builtin_amdgcn_s_setprio(1);
    mfmaPair(6, a00, a01);
    mfmaPair(7, a10, a11);
    __builtin_amdgcn_s_setprio(0);
    __builtin_amdgcn_sched_barrier(0);
    // everything for t+1 landed; t+2's 7 newest (+ blk3(t+2) next ph1) stay in flight
    if (t + 2 < NT) { asm volatile("s_waitcnt vmcnt(7)" ::: "memory"); }
    else            { asm volatile("s_waitcnt vmcnt(0)" ::: "memory"); }
    __builtin_amdgcn_s_barrier();
  }

  // epilogue
#pragma unroll
  for (int m = 0; m < 8; ++m)
#pragma unroll
    for (int n = 0; n < 4; ++n) {
      size_t row = rowBase + wr * 128 + m * 16 + g * 4;
      size_t col = colBase + wc * 64 + n * 16 + c;
#pragma unroll
      for (int r = 0; r < 4; ++r)
        storeC(&C[(row + r) * (size_t)N + col], acc[m][n][r]);
    }
}

// ---------------- RoPE on q,k; writes Q,K in [B,H,S,HD] --------------------
__global__ void rope_qk(const u16* __restrict__ qkv, const float* __restrict__ tab,
                        u16* __restrict__ Q, u16* __restrict__ K) {
  int idx = blockIdx.x * 256 + threadIdx.x;
  int j = idx & 63;
  int s = (idx >> 6) & (S_LEN - 1);
  int h = (idx >> 17) & (NH - 1);
  int b = idx >> 21;
  float cs = tab[s * 64 + j];
  float sn = tab[131072 + s * 64 + j];
  size_t qbase = (((size_t)(b * S_LEN + s) * 3 + 0) * NH + h) * HD;
  size_t kbase = qbase + (size_t)NH * HD;
  size_t o = ((size_t)(b * NH + h) * S_LEN + s) * HD;
  float q1 = bf2f(qkv[qbase + j]),  q2 = bf2f(qkv[qbase + j + 64]);
  Q[o + j]      = f2bf(q1 * cs - q2 * sn);
  Q[o + j + 64] = f2bf(q2 * cs + q1 * sn);
  float k1 = bf2f(qkv[kbase + j]), k2 = bf2f(qkv[kbase + j + 64]);
  K[o + j]      = f2bf(k1 * cs - k2 * sn);
  K[o + j + 64] = f2bf(k2 * cs + k1 * sn);
}

// ---------------- V transpose: qkv v-slot -> Vt [B,H,HD,S] -----------------
__global__ void v_transpose(const u16* __restrict__ qkv, u16* __restrict__ Vt) {
  __shared__ u16 t[32][33];
  int bh = blockIdx.z;
  int s0 = blockIdx.x * 32;
  int d0 = blockIdx.y * 32;
  int b = bh >> 4, h = bh & 15;
  int col = threadIdx.x & 31;
  int row = threadIdx.x >> 5;
#pragma unroll
  for (int i = 0; i < 4; ++i) {
    int s = row + i * 8;
    t[s][col] = qkv[(((size_t)(b * S_LEN + s0 + s) * 3 + 2) * NH + h) * HD + d0 + col];
  }
  __syncthreads();
  size_t vb = ((size_t)bh * HD + d0) * S_LEN + s0;
#pragma unroll
  for (int i = 0; i < 4; ++i) {
    int d = row + i * 8;
    Vt[vb + (size_t)d * S_LEN + col] = t[col][d];
  }
}

// ---------------- causal flash attention: 8-wave block, LDS-staged K/V -----
__global__ __launch_bounds__(512, 4) void attn_fwd(const u16* __restrict__ Q, const u16* __restrict__ K,
                                                   const u16* __restrict__ Vt, u16* __restrict__ O) {
  __shared__ alignas(16) u16 Ks[2 * 64 * 128];
  __shared__ alignas(16) u16 Vs[2 * 128 * 64];
  __shared__ alignas(16) u16 Pl[8 * 16 * 64];
  const int tid = threadIdx.x;
  const int lane = tid & 63;
  const int w = tid >> 6;
  const int g = lane >> 4, c = lane & 15;
  const int bh = blockIdx.x;
  const int pair = blockIdx.y;
  const int b = bh >> 4, h = bh & 15;

  const u16* Qb = Q + (size_t)bh * S_LEN * HD;
  const u16* Kb = K + (size_t)bh * S_LEN * HD;
  const u16* Vb = Vt + (size_t)bh * HD * S_LEN;
  const float SL = 0.12751753f;
  const int swz = (c & 7) << 4;

  int ldsOff[2], srcK[2], srcV[2];
#pragma unroll
  for (int ii = 0; ii < 2; ++ii) {
    int p = (w * 2 + ii) * 1024 + lane * 16;
    ldsOff[ii] = p;
    int rk = p >> 8, ik = p & 255;
    srcK[ii] = rk * 256 + (ik ^ ((rk & 7) << 4));
    int rv = p >> 7, iv = p & 127;
    srcV[ii] = rv * (S_LEN * 2) + (iv ^ ((rv & 7) << 4));
  }
  int koff[4], voff[2];
#pragma unroll
  for (int kb = 0; kb < 4; ++kb) koff[kb] = (kb * 64 + g * 16) ^ swz;
  voff[0] = (g * 16) ^ swz;
  voff[1] = (64 + g * 16) ^ swz;
  int poff[4];
#pragma unroll
  for (int t = 0; t < 4; ++t) poff[t] = (t * 32 + g * 8) ^ swz;
  char* Pw = (char*)Pl + w * 2048;

#pragma unroll 1
  for (int ph = 0; ph < 2; ++ph) {
    const int sti = ph ? (15 - pair) : pair;
    const int qb0 = sti * 128;
    const int q0 = qb0 + w * 16;

    bf16x8 qf[4];
#pragma unroll
    for (int kb = 0; kb < 4; ++kb)
      qf[kb] = *(const bf16x8*)&Qb[(size_t)(q0 + c) * HD + kb * 32 + g * 8];

    f32x4 acc[8];
#pragma unroll
    for (int cb = 0; cb < 8; ++cb) acc[cb] = f32x4{0.f, 0.f, 0.f, 0.f};
    float m_i = -3e38f, l_i = 0.f;

    const int nsteps = sti * 2 + 2;
#pragma unroll
    for (int ii = 0; ii < 2; ++ii) {
      __builtin_amdgcn_global_load_lds((const AS1 void*)((const char*)Kb + srcK[ii]),
                                       (AS3 void*)((char*)Ks + ldsOff[ii] - lane * 16), 16, 0, 0);
      __builtin_amdgcn_global_load_lds((const AS1 void*)((const char*)Vb + srcV[ii]),
                                       (AS3 void*)((char*)Vs + ldsOff[ii] - lane * 16), 16, 0, 0);
    }
    __syncthreads();
    int cur = 0;

#pragma unroll 1
    for (int st = 0; st < nsteps; ++st) {
      const int kv0 = st << 6;
      if (st + 1 < nsteps) {
        const char* kbase = (const char*)Kb + (size_t)(kv0 + 64) * 256;
        const char* vbase = (const char*)Vb + (size_t)(kv0 + 64) * 2;
        const int nb = (cur ^ 1) * 16384;
#pragma unroll
        for (int ii = 0; ii < 2; ++ii) {
          __builtin_amdgcn_global_load_lds((const AS1 void*)(kbase + srcK[ii]),
                                           (AS3 void*)((char*)Ks + nb + ldsOff[ii] - lane * 16), 16, 0, 0);
          __builtin_amdgcn_global_load_lds((const AS1 void*)(vbase + srcV[ii]),
                                           (AS3 void*)((char*)Vs + nb + ldsOff[ii] - lane * 16), 16, 0, 0);
        }
      }
      if (kv0 < q0 + 16) {
        const char* Kt = (const char*)Ks + cur * 16384;
        const char* Vtl = (const char*)Vs + cur * 16384;
        f32x4 s[4];
#pragma unroll
        for (int t = 0; t < 4; ++t) s[t] = f32x4{0.f, 0.f, 0.f, 0.f};
#pragma unroll
        for (int t = 0; t < 4; ++t)
#pragma unroll
          for (int kb = 0; kb < 4; ++kb) {
            bf16x8 kf = *(const bf16x8*)(Kt + t * 4096 + c * 256 + koff[kb]);
            s[t] = __builtin_amdgcn_mfma_f32_16x16x32_bf16(kf, qf[kb], s[t], 0, 0, 0);
          }
        if (kv0 + 63 > q0) {
          const int lim = q0 + c - kv0 - 4 * g;
#pragma unroll
          for (int t = 0; t < 4; ++t)
#pragma unroll
            for (int r = 0; r < 4; ++r)
              s[t][r] = (16 * t + r <= lim) ? s[t][r] : -3e38f;
        }
        float mx = s[0][0];
#pragma unroll
        for (int t = 0; t < 4; ++t)
#pragma unroll
          for (int r = 0; r < 4; ++r) mx = fmaxf(mx, s[t][r]);
        mx = fmaxf(mx, __shfl_xor(mx, 16));
        mx = fmaxf(mx, __shfl_xor(mx, 32));
        const float mn = fmaxf(m_i, mx);
        const float alpha = exp2f((m_i - mn) * SL);
        float rs = 0.f;
#pragma unroll
        for (int t = 0; t < 4; ++t) {
          float p0 = exp2f((s[t][0] - mn) * SL);
          float p1 = exp2f((s[t][1] - mn) * SL);
          float p2 = exp2f((s[t][2] - mn) * SL);
          float p3 = exp2f((s[t][3] - mn) * SL);
          rs += (p0 + p1) + (p2 + p3);
          ushort4 pw;
          pw.x = f2bf(p0); pw.y = f2bf(p1); pw.z = f2bf(p2); pw.w = f2bf(p3);
          *(ushort4*)(Pw + c * 128 + poff[t]) = pw;
        }
        rs += __shfl_xor(rs, 16);
        rs += __shfl_xor(rs, 32);
        l_i = l_i * alpha + rs;
        m_i = mn;
        float ar[4];
#pragma unroll
        for (int r = 0; r < 4; ++r) ar[r] = __shfl(alpha, 4 * g + r);
#pragma unroll
        for (int cb = 0; cb < 8; ++cb)
#pragma unroll
          for (int r = 0; r < 4; ++r) acc[cb][r] *= ar[r];
        bf16x8 pa0 = *(const bf16x8*)(Pw + c * 128 + voff[0]);
        bf16x8 pa1 = *(const bf16x8*)(Pw + c * 128 + voff[1]);
#pragma unroll
        for (int cb = 0; cb < 8; ++cb) {
          bf16x8 vf0 = *(const bf16x8*)(Vtl + cb * 2048 + c * 128 + voff[0]);
          acc[cb] = __builtin_amdgcn_mfma_f32_16x16x32_bf16(pa0, vf0, acc[cb], 0, 0, 0);
          bf16x8 vf1 = *(const bf16x8*)(Vtl + cb * 2048 + c * 128 + voff[1]);
          acc[cb] = __builtin_amdgcn_mfma_f32_16x16x32_bf16(pa1, vf1, acc[cb], 0, 0, 0);
        }
      }
      __syncthreads();
      cur ^= 1;
    }
    float linv = 1.0f / l_i;
    float lr[4];
#pragma unroll
    for (int r = 0; r < 4; ++r) lr[r] = __shfl(linv, 4 * g + r);
#pragma unroll
    for (int cb = 0; cb < 8; ++cb)
#pragma unroll
      for (int r = 0; r < 4; ++r) {
        int q = q0 + 4 * g + r;
        O[(((size_t)b * S_LEN + q) * NH + h) * HD + cb * 16 + c] = f2bf(acc[cb][r] * lr[r]);
      }
  }
}

// ---------------------------------------------------------------------------
extern "C" void kernel_launch(void* const* d_in, const int* in_sizes, int n_in,
                              void* d_out, int out_size, void* d_ws, size_t ws_size,
                              hipStream_t stream) {
  const float* x    = (const float*)d_in[0];
  const float* wqkv = (const float*)d_in[1];
  const float* wo   = (const float*)d_in[2];
  float* out = (float*)d_out;
  char* ws = (char*)d_ws;

  u16*  xb    = (u16*)(ws + 0);            // reused as attn out later
  u16*  wqkvb = (u16*)(ws + 33554432);
  float* tab  = (float*)(ws + 58720256);   // unioned with wob (tab dead after rope)
  u16*  wob   = (u16*)(ws + 58720256);
  u16*  qkvb  = (u16*)(ws + 67108864);
  u16*  Vt    = (u16*)(ws + 167772160);
  u16*  attn  = (u16*)(ws + 0);
  u16*  Qr = (u16*)d_out;                  // d_out scratch: dead before GEMM2
  u16*  Kr = (u16*)d_out + 16777216;

  cvt_f32_bf16<<<16384, 256, 0, stream>>>(x, xb, 16777216 / 4);
  cvt_f32_bf16<<<12288, 256, 0, stream>>>(wqkv, wqkvb, 12582912 / 4);
  build_tab<<<512, 256, 0, stream>>>(tab);

  // qkv = x @ wqkv^T : M=8192, N=6144, K=2048 -> 24x32 = 768 blocks
  gemm_bt4<u16><<<768, 512, 0, stream>>>(xb, wqkvb, qkvb, 8192, 6144, 2048, 24);

  rope_qk<<<32768, 256, 0, stream>>>(qkvb, tab, Qr, Kr);
  v_transpose<<<dim3(64, 4, 64), 256, 0, stream>>>(qkvb, Vt);

  cvt_f32_bf16<<<4096, 256, 0, stream>>>(wo, wob, 4194304 / 4);

  attn_fwd<<<dim3(64, 8), 512, 0, stream>>>(Qr, Kr, Vt, attn);

  // out = attn @ wo^T : M=8192, N=2048, K=2048 -> 8x32 = 256 blocks
  gemm_bt4<float><<<256, 512, 0, stream>>>(attn, wob, out, 8192, 2048, 2048, 8);
}

// Round 7
// 451.342 us; speedup vs baseline: 1.2985x; 1.0316x over previous
//
#include <hip/hip_runtime.h>

typedef unsigned short u16;
typedef unsigned int u32;
typedef __bf16 bf16x8 __attribute__((ext_vector_type(8)));
typedef float f32x4 __attribute__((ext_vector_type(4)));

#define S_LEN 2048
#define NH 16
#define HD 128

#define AS1 __attribute__((address_space(1)))
#define AS3 __attribute__((address_space(3)))

__device__ __forceinline__ u16 f2bf(float x) {
  u32 u = __builtin_bit_cast(u32, x);
  u32 r = u + 0x7FFFu + ((u >> 16) & 1u);  // RNE
  return (u16)(r >> 16);
}
__device__ __forceinline__ float bf2f(u16 b) {
  return __builtin_bit_cast(float, (u32)b << 16);
}

// ---------------- fp32 -> bf16 conversion (vectorized, G13) ----------------
__global__ void cvt_f32_bf16(const float* __restrict__ in, u16* __restrict__ out, int n4) {
  int i = blockIdx.x * 256 + threadIdx.x;
  if (i >= n4) return;
  float4 v = ((const float4*)in)[i];
  ushort4 o;
  o.x = f2bf(v.x); o.y = f2bf(v.y); o.z = f2bf(v.z); o.w = f2bf(v.w);
  ((ushort4*)out)[i] = o;
}

// ---------------- RoPE cos/sin table ----------------------------------------
__global__ void build_tab(float* __restrict__ tab) {
  int t = blockIdx.x * 256 + threadIdx.x;
  int s = t >> 6, j = t & 63;
  float inv = exp2f(-(float)j * 0.20762050593045083f);
  float ang = (float)s * inv;
  tab[t] = cosf(ang);
  tab[131072 + t] = sinf(ang);
}

// ---------------- GEMM: C[M,N] = A[M,K]*B[N,K]^T ----------------------------
// 256x256 tile, BK=64, 8 waves (2x4). LDS 128KiB dbuf2. 3-bit row-XOR swizzle
// (col_byte ^= (row&7)<<4): per 16-lane LDS phase, 8x2 coverage of 32 banks
// = conflict-free. 4 phases/K-tile, 16 MFMA each; distance-2 staging;
// boundary vmcnt(7) (never drained in steady state); setprio around MFMA.
__device__ __forceinline__ void storeC(u16* p, float v) { *p = f2bf(v); }
__device__ __forceinline__ void storeC(float* p, float v) { *p = v; }

template <typename OutT>
__global__ __launch_bounds__(512, 2) void gemm_bt5(const u16* __restrict__ A, const u16* __restrict__ B,
                                                   OutT* __restrict__ C, int M, int N, int K, int nbx) {
  __shared__ alignas(16) u16 LDS[65536];  // 128 KiB
  char* lds = (char*)LDS;
  const int tid = threadIdx.x;
  const int lane = tid & 63;
  const int w = tid >> 6;              // 0..7
  const int wr = w >> 2, wc = w & 3;   // 2 x 4 wave grid
  const int g = lane >> 4, c = lane & 15;

  // XCD-aware bijective swizzle (nwg multiple of 8)
  const int nwg = gridDim.x;
  const int id = blockIdx.x;
  const int sw = (id & 7) * (nwg >> 3) + (id >> 3);
  const int bx = sw % nbx, by = sw / nbx;
  const size_t rowBase = (size_t)by * 256;
  const size_t colBase = (size_t)bx * 256;

  const int half = w & 1;              // which 128-row half this wave stages
  const int sub = (w >> 1) & 3;        // 0..3
  const size_t ldb = (size_t)K * 2;    // row stride in bytes
  // per-lane source for one gload instr (1KB = 8 rows x 128B), srow = lane>>3.
  // LDS dest is linear: phys cb = (lane&7)*16. Logical col living there:
  // cb ^ ((row&7)<<4) with row&7 == srow  ->  (((lane&7) ^ srow) << 4).
  const int srow = lane >> 3;
  const int soff = ((lane & 7) ^ srow) << 4;
  const char* ApS = (const char*)A + (rowBase + half * 128 + srow) * ldb + soff;
  const char* BpS = (const char*)B + (colBase + half * 128 + srow) * ldb + soff;

  auto stA = [&](int u, int blk) {  // stage A rows [blk*32+sub*8, +8) of half, tile u
    const int r0 = blk * 32 + sub * 8;
    const int dst = ((u & 1) * 2 + half) * 16384 + r0 * 128;
    __builtin_amdgcn_global_load_lds((const AS1 void*)(ApS + (size_t)r0 * ldb + (size_t)u * 128),
                                     (AS3 void*)(lds + dst), 16, 0, 0);
  };
  auto stB = [&](int u, int jj) {   // stage B rows [ (sub*4+jj)*8, +8) of half, tile u
    const int r0 = (sub * 4 + jj) * 8;
    const int dst = 65536 + ((u & 1) * 2 + half) * 16384 + r0 * 128;
    __builtin_amdgcn_global_load_lds((const AS1 void*)(BpS + (size_t)r0 * ldb + (size_t)u * 128),
                                     (AS3 void*)(lds + dst), 16, 0, 0);
  };

  const int swz = (c & 7) << 4;  // 3-bit read-side swizzle (row&7 == c&7)
  auto rdA = [&](int bA, int mi, int kk) -> bf16x8 {
    return *(const bf16x8*)(lds + bA + mi * 2048 + c * 128 + ((kk * 64 + g * 16) ^ swz));
  };
  auto rdB = [&](int bB, int n, int kk) -> bf16x8 {
    return *(const bf16x8*)(lds + bB + n * 2048 + c * 128 + ((kk * 64 + g * 16) ^ swz));
  };

  f32x4 acc[8][4];
#pragma unroll
  for (int m = 0; m < 8; ++m)
#pragma unroll
    for (int n = 0; n < 4; ++n) acc[m][n] = f32x4{0.f, 0.f, 0.f, 0.f};

  bf16x8 bf_[4][2];
  auto mfmaPair = [&](int mi, bf16x8 ak0, bf16x8 ak1) {
#pragma unroll
    for (int n = 0; n < 4; ++n) {
      acc[mi][n] = __builtin_amdgcn_mfma_f32_16x16x32_bf16(ak0, bf_[n][0], acc[mi][n], 0, 0, 0);
      acc[mi][n] = __builtin_amdgcn_mfma_f32_16x16x32_bf16(ak1, bf_[n][1], acc[mi][n], 0, 0, 0);
    }
  };

  const int NT = K >> 6;  // BK=64

  // prologue: fully stage tiles 0 and 1 (16 instr), wait tile 0 (8 left in flight)
#pragma unroll
  for (int b = 0; b < 4; ++b) stA(0, b);
#pragma unroll
  for (int j = 0; j < 4; ++j) stB(0, j);
#pragma unroll
  for (int b = 0; b < 4; ++b) stA(1, b);
#pragma unroll
  for (int j = 0; j < 4; ++j) stB(1, j);
  asm volatile("s_waitcnt vmcnt(8)" ::: "memory");
  __builtin_amdgcn_s_barrier();

#pragma unroll 1
  for (int t = 0; t < NT; ++t) {
    const int bA = (t & 1) * 32768 + wr * 16384;
    const int bB = 65536 + (t & 1) * 32768 + (wc >> 1) * 16384 + (wc & 1) * 8192;
    bf16x8 a00, a01, a10, a11;
    // ---- phase 1: A m0,m1 (4 reads) + all B (8 reads); stage A-blk3 of t+1
    a00 = rdA(bA, 0, 0); a01 = rdA(bA, 0, 1); a10 = rdA(bA, 1, 0); a11 = rdA(bA, 1, 1);
#pragma unroll
    for (int n = 0; n < 4; ++n) { bf_[n][0] = rdB(bB, n, 0); bf_[n][1] = rdB(bB, n, 1); }
    if (t >= 1 && t + 1 < NT) stA(t + 1, 3);
    __builtin_amdgcn_s_barrier();
    asm volatile("s_waitcnt lgkmcnt(0)" ::: "memory");
    __builtin_amdgcn_sched_barrier(0);
    __builtin_amdgcn_s_setprio(1);
    mfmaPair(0, a00, a01);
    mfmaPair(1, a10, a11);
    __builtin_amdgcn_s_setprio(0);
    __builtin_amdgcn_sched_barrier(0);
    __builtin_amdgcn_s_barrier();
    // ---- phase 2: A m2,m3; stage A-blk0(t+2) + B 2 units
    a00 = rdA(bA, 2, 0); a01 = rdA(bA, 2, 1); a10 = rdA(bA, 3, 0); a11 = rdA(bA, 3, 1);
    if (t + 2 < NT) { stA(t + 2, 0); stB(t + 2, 0); stB(t + 2, 1); }
    __builtin_amdgcn_s_barrier();
    asm volatile("s_waitcnt lgkmcnt(0)" ::: "memory");
    __builtin_amdgcn_sched_barrier(0);
    __builtin_amdgcn_s_setprio(1);
    mfmaPair(2, a00, a01);
    mfmaPair(3, a10, a11);
    __builtin_amdgcn_s_setprio(0);
    __builtin_amdgcn_sched_barrier(0);
    __builtin_amdgcn_s_barrier();
    // ---- phase 3: A m4,m5; stage A-blk1(t+2) + B 2 units
    a00 = rdA(bA, 4, 0); a01 = rdA(bA, 4, 1); a10 = rdA(bA, 5, 0); a11 = rdA(bA, 5, 1);
    if (t + 2 < NT) { stA(t + 2, 1); stB(t + 2, 2); stB(t + 2, 3); }
    __builtin_amdgcn_s_barrier();
    asm volatile("s_waitcnt lgkmcnt(0)" ::: "memory");
    __builtin_amdgcn_sched_barrier(0);
    __builtin_amdgcn_s_setprio(1);
    mfmaPair(4, a00, a01);
    mfmaPair(5, a10, a11);
    __builtin_amdgcn_s_setprio(0);
    __builtin_amdgcn_sched_barrier(0);
    __builtin_amdgcn_s_barrier();
    // ---- phase 4: A m6,m7; stage A-blk2(t+2); boundary counted vmcnt
    a00 = rdA(bA, 6, 0); a01 = rdA(bA, 6, 1); a10 = rdA(bA, 7, 0); a11 = rdA(bA, 7, 1);
    if (t + 2 < NT) stA(t + 2, 2);
    __builtin_amdgcn_s_barrier();
    asm volatile("s_waitcnt lgkmcnt(0)" ::: "memory");
    __builtin_amdgcn_sched_barrier(0);
    __builtin_amdgcn_s_setprio(1);
    mfmaPair(6, a00, a01);
    mfmaPair(7, a10, a11);
    __builtin_amdgcn_s_setprio(0);
    __builtin_amdgcn_sched_barrier(0);
    if (t + 2 < NT) { asm volatile("s_waitcnt vmcnt(7)" ::: "memory"); }
    else            { asm volatile("s_waitcnt vmcnt(0)" ::: "memory"); }
    __builtin_amdgcn_s_barrier();
  }

  // epilogue
#pragma unroll
  for (int m = 0; m < 8; ++m)
#pragma unroll
    for (int n = 0; n < 4; ++n) {
      size_t row = rowBase + wr * 128 + m * 16 + g * 4;
      size_t col = colBase + wc * 64 + n * 16 + c;
#pragma unroll
      for (int r = 0; r < 4; ++r)
        storeC(&C[(row + r) * (size_t)N + col], acc[m][n][r]);
    }
}

// ---------------- RoPE on q,k; writes Q,K in [B,H,S,HD] --------------------
__global__ void rope_qk(const u16* __restrict__ qkv, const float* __restrict__ tab,
                        u16* __restrict__ Q, u16* __restrict__ K) {
  int idx = blockIdx.x * 256 + threadIdx.x;
  int j = idx & 63;
  int s = (idx >> 6) & (S_LEN - 1);
  int h = (idx >> 17) & (NH - 1);
  int b = idx >> 21;
  float cs = tab[s * 64 + j];
  float sn = tab[131072 + s * 64 + j];
  size_t qbase = (((size_t)(b * S_LEN + s) * 3 + 0) * NH + h) * HD;
  size_t kbase = qbase + (size_t)NH * HD;
  size_t o = ((size_t)(b * NH + h) * S_LEN + s) * HD;
  float q1 = bf2f(qkv[qbase + j]),  q2 = bf2f(qkv[qbase + j + 64]);
  Q[o + j]      = f2bf(q1 * cs - q2 * sn);
  Q[o + j + 64] = f2bf(q2 * cs + q1 * sn);
  float k1 = bf2f(qkv[kbase + j]), k2 = bf2f(qkv[kbase + j + 64]);
  K[o + j]      = f2bf(k1 * cs - k2 * sn);
  K[o + j + 64] = f2bf(k2 * cs + k1 * sn);
}

// ---------------- V transpose: qkv v-slot -> Vt [B,H,HD,S] -----------------
__global__ void v_transpose(const u16* __restrict__ qkv, u16* __restrict__ Vt) {
  __shared__ u16 t[32][33];
  int bh = blockIdx.z;
  int s0 = blockIdx.x * 32;
  int d0 = blockIdx.y * 32;
  int b = bh >> 4, h = bh & 15;
  int col = threadIdx.x & 31;
  int row = threadIdx.x >> 5;
#pragma unroll
  for (int i = 0; i < 4; ++i) {
    int s = row + i * 8;
    t[s][col] = qkv[(((size_t)(b * S_LEN + s0 + s) * 3 + 2) * NH + h) * HD + d0 + col];
  }
  __syncthreads();
  size_t vb = ((size_t)bh * HD + d0) * S_LEN + s0;
#pragma unroll
  for (int i = 0; i < 4; ++i) {
    int d = row + i * 8;
    Vt[vb + (size_t)d * S_LEN + col] = t[col][d];
  }
}

// ---------------- causal flash attention: 8-wave block, LDS-staged K/V -----
__global__ __launch_bounds__(512, 4) void attn_fwd(const u16* __restrict__ Q, const u16* __restrict__ K,
                                                   const u16* __restrict__ Vt, u16* __restrict__ O) {
  __shared__ alignas(16) u16 Ks[2 * 64 * 128];
  __shared__ alignas(16) u16 Vs[2 * 128 * 64];
  __shared__ alignas(16) u16 Pl[8 * 16 * 64];
  const int tid = threadIdx.x;
  const int lane = tid & 63;
  const int w = tid >> 6;
  const int g = lane >> 4, c = lane & 15;
  const int bh = blockIdx.x;
  const int pair = blockIdx.y;
  const int b = bh >> 4, h = bh & 15;

  const u16* Qb = Q + (size_t)bh * S_LEN * HD;
  const u16* Kb = K + (size_t)bh * S_LEN * HD;
  const u16* Vb = Vt + (size_t)bh * HD * S_LEN;
  const float SL = 0.12751753f;
  const int swz = (c & 7) << 4;

  int ldsOff[2], srcK[2], srcV[2];
#pragma unroll
  for (int ii = 0; ii < 2; ++ii) {
    int p = (w * 2 + ii) * 1024 + lane * 16;
    ldsOff[ii] = p;
    int rk = p >> 8, ik = p & 255;
    srcK[ii] = rk * 256 + (ik ^ ((rk & 7) << 4));
    int rv = p >> 7, iv = p & 127;
    srcV[ii] = rv * (S_LEN * 2) + (iv ^ ((rv & 7) << 4));
  }
  int koff[4], voff[2];
#pragma unroll
  for (int kb = 0; kb < 4; ++kb) koff[kb] = (kb * 64 + g * 16) ^ swz;
  voff[0] = (g * 16) ^ swz;
  voff[1] = (64 + g * 16) ^ swz;
  int poff[4];
#pragma unroll
  for (int t = 0; t < 4; ++t) poff[t] = (t * 32 + g * 8) ^ swz;
  char* Pw = (char*)Pl + w * 2048;

#pragma unroll 1
  for (int ph = 0; ph < 2; ++ph) {
    const int sti = ph ? (15 - pair) : pair;
    const int qb0 = sti * 128;
    const int q0 = qb0 + w * 16;

    bf16x8 qf[4];
#pragma unroll
    for (int kb = 0; kb < 4; ++kb)
      qf[kb] = *(const bf16x8*)&Qb[(size_t)(q0 + c) * HD + kb * 32 + g * 8];

    f32x4 acc[8];
#pragma unroll
    for (int cb = 0; cb < 8; ++cb) acc[cb] = f32x4{0.f, 0.f, 0.f, 0.f};
    float m_i = -3e38f, l_i = 0.f;

    const int nsteps = sti * 2 + 2;
#pragma unroll
    for (int ii = 0; ii < 2; ++ii) {
      __builtin_amdgcn_global_load_lds((const AS1 void*)((const char*)Kb + srcK[ii]),
                                       (AS3 void*)((char*)Ks + ldsOff[ii] - lane * 16), 16, 0, 0);
      __builtin_amdgcn_global_load_lds((const AS1 void*)((const char*)Vb + srcV[ii]),
                                       (AS3 void*)((char*)Vs + ldsOff[ii] - lane * 16), 16, 0, 0);
    }
    __syncthreads();
    int cur = 0;

#pragma unroll 1
    for (int st = 0; st < nsteps; ++st) {
      const int kv0 = st << 6;
      if (st + 1 < nsteps) {
        const char* kbase = (const char*)Kb + (size_t)(kv0 + 64) * 256;
        const char* vbase = (const char*)Vb + (size_t)(kv0 + 64) * 2;
        const int nb = (cur ^ 1) * 16384;
#pragma unroll
        for (int ii = 0; ii < 2; ++ii) {
          __builtin_amdgcn_global_load_lds((const AS1 void*)(kbase + srcK[ii]),
                                           (AS3 void*)((char*)Ks + nb + ldsOff[ii] - lane * 16), 16, 0, 0);
          __builtin_amdgcn_global_load_lds((const AS1 void*)(vbase + srcV[ii]),
                                           (AS3 void*)((char*)Vs + nb + ldsOff[ii] - lane * 16), 16, 0, 0);
        }
      }
      if (kv0 < q0 + 16) {
        const char* Kt = (const char*)Ks + cur * 16384;
        const char* Vtl = (const char*)Vs + cur * 16384;
        f32x4 s[4];
#pragma unroll
        for (int t = 0; t < 4; ++t) s[t] = f32x4{0.f, 0.f, 0.f, 0.f};
#pragma unroll
        for (int t = 0; t < 4; ++t)
#pragma unroll
          for (int kb = 0; kb < 4; ++kb) {
            bf16x8 kf = *(const bf16x8*)(Kt + t * 4096 + c * 256 + koff[kb]);
            s[t] = __builtin_amdgcn_mfma_f32_16x16x32_bf16(kf, qf[kb], s[t], 0, 0, 0);
          }
        if (kv0 + 63 > q0) {
          const int lim = q0 + c - kv0 - 4 * g;
#pragma unroll
          for (int t = 0; t < 4; ++t)
#pragma unroll
            for (int r = 0; r < 4; ++r)
              s[t][r] = (16 * t + r <= lim) ? s[t][r] : -3e38f;
        }
        float mx = s[0][0];
#pragma unroll
        for (int t = 0; t < 4; ++t)
#pragma unroll
          for (int r = 0; r < 4; ++r) mx = fmaxf(mx, s[t][r]);
        mx = fmaxf(mx, __shfl_xor(mx, 16));
        mx = fmaxf(mx, __shfl_xor(mx, 32));
        const float mn = fmaxf(m_i, mx);
        const float alpha = exp2f((m_i - mn) * SL);
        float rs = 0.f;
#pragma unroll
        for (int t = 0; t < 4; ++t) {
          float p0 = exp2f((s[t][0] - mn) * SL);
          float p1 = exp2f((s[t][1] - mn) * SL);
          float p2 = exp2f((s[t][2] - mn) * SL);
          float p3 = exp2f((s[t][3] - mn) * SL);
          rs += (p0 + p1) + (p2 + p3);
          ushort4 pw;
          pw.x = f2bf(p0); pw.y = f2bf(p1); pw.z = f2bf(p2); pw.w = f2bf(p3);
          *(ushort4*)(Pw + c * 128 + poff[t]) = pw;
        }
        rs += __shfl_xor(rs, 16);
        rs += __shfl_xor(rs, 32);
        l_i = l_i * alpha + rs;
        m_i = mn;
        float ar[4];
#pragma unroll
        for (int r = 0; r < 4; ++r) ar[r] = __shfl(alpha, 4 * g + r);
#pragma unroll
        for (int cb = 0; cb < 8; ++cb)
#pragma unroll
          for (int r = 0; r < 4; ++r) acc[cb][r] *= ar[r];
        bf16x8 pa0 = *(const bf16x8*)(Pw + c * 128 + voff[0]);
        bf16x8 pa1 = *(const bf16x8*)(Pw + c * 128 + voff[1]);
#pragma unroll
        for (int cb = 0; cb < 8; ++cb) {
          bf16x8 vf0 = *(const bf16x8*)(Vtl + cb * 2048 + c * 128 + voff[0]);
          acc[cb] = __builtin_amdgcn_mfma_f32_16x16x32_bf16(pa0, vf0, acc[cb], 0, 0, 0);
          bf16x8 vf1 = *(const bf16x8*)(Vtl + cb * 2048 + c * 128 + voff[1]);
          acc[cb] = __builtin_amdgcn_mfma_f32_16x16x32_bf16(pa1, vf1, acc[cb], 0, 0, 0);
        }
      }
      __syncthreads();
      cur ^= 1;
    }
    float linv = 1.0f / l_i;
    float lr[4];
#pragma unroll
    for (int r = 0; r < 4; ++r) lr[r] = __shfl(linv, 4 * g + r);
#pragma unroll
    for (int cb = 0; cb < 8; ++cb)
#pragma unroll
      for (int r = 0; r < 4; ++r) {
        int q = q0 + 4 * g + r;
        O[(((size_t)b * S_LEN + q) * NH + h) * HD + cb * 16 + c] = f2bf(acc[cb][r] * lr[r]);
      }
  }
}

// ---------------------------------------------------------------------------
extern "C" void kernel_launch(void* const* d_in, const int* in_sizes, int n_in,
                              void* d_out, int out_size, void* d_ws, size_t ws_size,
                              hipStream_t stream) {
  const float* x    = (const float*)d_in[0];
  const float* wqkv = (const float*)d_in[1];
  const float* wo   = (const float*)d_in[2];
  float* out = (float*)d_out;
  char* ws = (char*)d_ws;

  u16*  xb    = (u16*)(ws + 0);            // reused as attn out later
  u16*  wqkvb = (u16*)(ws + 33554432);
  float* tab  = (float*)(ws + 58720256);   // unioned with wob (tab dead after rope)
  u16*  wob   = (u16*)(ws + 58720256);
  u16*  qkvb  = (u16*)(ws + 67108864);
  u16*  Vt    = (u16*)(ws + 167772160);
  u16*  attn  = (u16*)(ws + 0);
  u16*  Qr = (u16*)d_out;                  // d_out scratch: dead before GEMM2
  u16*  Kr = (u16*)d_out + 16777216;

  cvt_f32_bf16<<<16384, 256, 0, stream>>>(x, xb, 16777216 / 4);
  cvt_f32_bf16<<<12288, 256, 0, stream>>>(wqkv, wqkvb, 12582912 / 4);
  build_tab<<<512, 256, 0, stream>>>(tab);

  // qkv = x @ wqkv^T : M=8192, N=6144, K=2048 -> 24x32 = 768 blocks
  gemm_bt5<u16><<<768, 512, 0, stream>>>(xb, wqkvb, qkvb, 8192, 6144, 2048, 24);

  rope_qk<<<32768, 256, 0, stream>>>(qkvb, tab, Qr, Kr);
  v_transpose<<<dim3(64, 4, 64), 256, 0, stream>>>(qkvb, Vt);

  cvt_f32_bf16<<<4096, 256, 0, stream>>>(wo, wob, 4194304 / 4);

  attn_fwd<<<dim3(64, 8), 512, 0, stream>>>(Qr, Kr, Vt, attn);

  // out = attn @ wo^T : M=8192, N=2048, K=2048 -> 8x32 = 256 blocks
  gemm_bt5<float><<<256, 512, 0, stream>>>(attn, wob, out, 8192, 2048, 2048, 8);
}

// Round 8
// 434.225 us; speedup vs baseline: 1.3497x; 1.0394x over previous
//
#include <hip/hip_runtime.h>

typedef unsigned short u16;
typedef unsigned int u32;
typedef __bf16 bf16x8 __attribute__((ext_vector_type(8)));
typedef float f32x4 __attribute__((ext_vector_type(4)));

#define S_LEN 2048
#define NH 16
#define HD 128

#define AS1 __attribute__((address_space(1)))
#define AS3 __attribute__((address_space(3)))

__device__ __forceinline__ u16 f2bf(float x) {
  u32 u = __builtin_bit_cast(u32, x);
  u32 r = u + 0x7FFFu + ((u >> 16) & 1u);  // RNE
  return (u16)(r >> 16);
}
__device__ __forceinline__ float bf2f(u16 b) {
  return __builtin_bit_cast(float, (u32)b << 16);
}

// ---------------- fp32 -> bf16 conversion (vectorized, G13) ----------------
__global__ void cvt_f32_bf16(const float* __restrict__ in, u16* __restrict__ out, int n4) {
  int i = blockIdx.x * 256 + threadIdx.x;
  if (i >= n4) return;
  float4 v = ((const float4*)in)[i];
  ushort4 o;
  o.x = f2bf(v.x); o.y = f2bf(v.y); o.z = f2bf(v.z); o.w = f2bf(v.w);
  ((ushort4*)out)[i] = o;
}

// ---------------- RoPE cos/sin table ----------------------------------------
__global__ void build_tab(float* __restrict__ tab) {
  int t = blockIdx.x * 256 + threadIdx.x;
  int s = t >> 6, j = t & 63;
  float inv = exp2f(-(float)j * 0.20762050593045083f);
  float ang = (float)s * inv;
  tab[t] = cosf(ang);
  tab[131072 + t] = sinf(ang);
}

// ---------------- GEMM: C[M,N] = A[M,K]*B[N,K]^T ----------------------------
// 256x256 tile, BK=64, 8 waves (2x4), LDS 128KiB dbuf2, conflict-free 3-bit
// row-XOR swizzle (verified: SQ_LDS_BANK_CONFLICT=0). NEW: ds_reads pipelined
// one phase ahead (aP/aQ register dbuf, counted lgkmcnt(4)) so the LDS pipe
// overlaps the MFMA pipe; 4 barriers/tile; distance-2 staging, vmcnt(7).
__device__ __forceinline__ void storeC(u16* p, float v) { *p = f2bf(v); }
__device__ __forceinline__ void storeC(float* p, float v) { *p = v; }

template <typename OutT>
__global__ __launch_bounds__(512, 2) void gemm_bt6(const u16* __restrict__ A, const u16* __restrict__ B,
                                                   OutT* __restrict__ C, int M, int N, int K, int nbx) {
  __shared__ alignas(16) u16 LDS[65536];  // 128 KiB
  char* lds = (char*)LDS;
  const int tid = threadIdx.x;
  const int lane = tid & 63;
  const int w = tid >> 6;              // 0..7
  const int wr = w >> 2, wc = w & 3;   // 2 x 4 wave grid
  const int g = lane >> 4, c = lane & 15;

  // XCD-aware bijective swizzle (nwg multiple of 8)
  const int nwg = gridDim.x;
  const int id = blockIdx.x;
  const int sw = (id & 7) * (nwg >> 3) + (id >> 3);
  const int bx = sw % nbx, by = sw / nbx;
  const size_t rowBase = (size_t)by * 256;
  const size_t colBase = (size_t)bx * 256;

  const int half = w & 1;
  const int sub = (w >> 1) & 3;
  const size_t ldb = (size_t)K * 2;
  const int srow = lane >> 3;
  const int soff = ((lane & 7) ^ srow) << 4;   // inverse 3-bit row-XOR
  const char* ApS = (const char*)A + (rowBase + half * 128 + srow) * ldb + soff;
  const char* BpS = (const char*)B + (colBase + half * 128 + srow) * ldb + soff;

  auto stA = [&](int u, int blk) {
    const int r0 = blk * 32 + sub * 8;
    const int dst = ((u & 1) * 2 + half) * 16384 + r0 * 128;
    __builtin_amdgcn_global_load_lds((const AS1 void*)(ApS + (size_t)r0 * ldb + (size_t)u * 128),
                                     (AS3 void*)(lds + dst), 16, 0, 0);
  };
  auto stB = [&](int u, int jj) {
    const int r0 = (sub * 4 + jj) * 8;
    const int dst = 65536 + ((u & 1) * 2 + half) * 16384 + r0 * 128;
    __builtin_amdgcn_global_load_lds((const AS1 void*)(BpS + (size_t)r0 * ldb + (size_t)u * 128),
                                     (AS3 void*)(lds + dst), 16, 0, 0);
  };

  const int swz = (c & 7) << 4;  // read-side swizzle (row&7 == c&7)
  auto rdA = [&](int bA, int mi, int kk) -> bf16x8 {
    return *(const bf16x8*)(lds + bA + mi * 2048 + c * 128 + ((kk * 64 + g * 16) ^ swz));
  };
  auto rdB = [&](int bB, int n, int kk) -> bf16x8 {
    return *(const bf16x8*)(lds + bB + n * 2048 + c * 128 + ((kk * 64 + g * 16) ^ swz));
  };

  f32x4 acc[8][4];
#pragma unroll
  for (int m = 0; m < 8; ++m)
#pragma unroll
    for (int n = 0; n < 4; ++n) acc[m][n] = f32x4{0.f, 0.f, 0.f, 0.f};

  bf16x8 bf_[4][2];
  bf16x8 aP[4], aQ[4];

  auto loadA = [&](bf16x8 (&s)[4], int bA, int mi) {
    s[0] = rdA(bA, mi, 0); s[1] = rdA(bA, mi, 1);
    s[2] = rdA(bA, mi + 1, 0); s[3] = rdA(bA, mi + 1, 1);
  };
  auto loadR1 = [&](int bA, int bB) {  // A m0,m1 + all B (12 reads)
    loadA(aP, bA, 0);
#pragma unroll
    for (int n = 0; n < 4; ++n) { bf_[n][0] = rdB(bB, n, 0); bf_[n][1] = rdB(bB, n, 1); }
  };
  auto MFMA2 = [&](int mi, bf16x8 (&s)[4]) {
#pragma unroll
    for (int n = 0; n < 4; ++n) {
      acc[mi][n]     = __builtin_amdgcn_mfma_f32_16x16x32_bf16(s[0], bf_[n][0], acc[mi][n], 0, 0, 0);
      acc[mi][n]     = __builtin_amdgcn_mfma_f32_16x16x32_bf16(s[1], bf_[n][1], acc[mi][n], 0, 0, 0);
      acc[mi + 1][n] = __builtin_amdgcn_mfma_f32_16x16x32_bf16(s[2], bf_[n][0], acc[mi + 1][n], 0, 0, 0);
      acc[mi + 1][n] = __builtin_amdgcn_mfma_f32_16x16x32_bf16(s[3], bf_[n][1], acc[mi + 1][n], 0, 0, 0);
    }
  };

  const int NT = K >> 6;  // BK=64

  // prologue: stage tiles 0,1 fully; wait tile 0; then issue R1(tile0)
#pragma unroll
  for (int b = 0; b < 4; ++b) stA(0, b);
#pragma unroll
  for (int j = 0; j < 4; ++j) stB(0, j);
#pragma unroll
  for (int b = 0; b < 4; ++b) stA(1, b);
#pragma unroll
  for (int j = 0; j < 4; ++j) stB(1, j);
  asm volatile("s_waitcnt vmcnt(8)" ::: "memory");
  __builtin_amdgcn_s_barrier();
  {
    const int bA0 = wr * 16384;
    const int bB0 = 65536 + (wc >> 1) * 16384 + (wc & 1) * 8192;
    loadR1(bA0, bB0);
  }

#pragma unroll 1
  for (int t = 0; t < NT; ++t) {
    const int bA = (t & 1) * 32768 + wr * 16384;
    const int bB = 65536 + (t & 1) * 32768 + (wc >> 1) * 16384 + (wc & 1) * 8192;
    // ---- phase 1: issue R2 (A m2,m3 -> aQ); MFMA m0,m1 from aP (R1)
    loadA(aQ, bA, 2);
    if (t >= 1 && t + 1 < NT) stA(t + 1, 3);
    asm volatile("s_waitcnt lgkmcnt(4)" ::: "memory");
    __builtin_amdgcn_sched_barrier(0);
    __builtin_amdgcn_s_setprio(1);
    MFMA2(0, aP);
    __builtin_amdgcn_s_setprio(0);
    __builtin_amdgcn_sched_barrier(0);
    __builtin_amdgcn_s_barrier();
    // ---- phase 2: issue R3 (A m4,m5 -> aP); MFMA m2,m3 from aQ
    loadA(aP, bA, 4);
    if (t + 2 < NT) { stA(t + 2, 0); stB(t + 2, 0); stB(t + 2, 1); }
    asm volatile("s_waitcnt lgkmcnt(4)" ::: "memory");
    __builtin_amdgcn_sched_barrier(0);
    __builtin_amdgcn_s_setprio(1);
    MFMA2(2, aQ);
    __builtin_amdgcn_s_setprio(0);
    __builtin_amdgcn_sched_barrier(0);
    __builtin_amdgcn_s_barrier();
    // ---- phase 3: issue R4 (A m6,m7 -> aQ); MFMA m4,m5 from aP
    loadA(aQ, bA, 6);
    if (t + 2 < NT) { stA(t + 2, 1); stB(t + 2, 2); stB(t + 2, 3); }
    asm volatile("s_waitcnt lgkmcnt(4)" ::: "memory");
    __builtin_amdgcn_sched_barrier(0);
    __builtin_amdgcn_s_setprio(1);
    MFMA2(4, aP);
    __builtin_amdgcn_s_setprio(0);
    __builtin_amdgcn_sched_barrier(0);
    __builtin_amdgcn_s_barrier();
    // ---- phase 4: MFMA m6,m7 from aQ; boundary
    if (t + 2 < NT) stA(t + 2, 2);
    asm volatile("s_waitcnt lgkmcnt(0)" ::: "memory");
    __builtin_amdgcn_sched_barrier(0);
    __builtin_amdgcn_s_setprio(1);
    MFMA2(6, aQ);
    __builtin_amdgcn_s_setprio(0);
    __builtin_amdgcn_sched_barrier(0);
    if (t + 2 < NT) { asm volatile("s_waitcnt vmcnt(7)" ::: "memory"); }
    else            { asm volatile("s_waitcnt vmcnt(0)" ::: "memory"); }
    __builtin_amdgcn_s_barrier();
    // ---- post-boundary: issue R1(t+1) (12 reads, land under next ph1)
    if (t + 1 < NT) {
      const int bA1 = ((t + 1) & 1) * 32768 + wr * 16384;
      const int bB1 = 65536 + ((t + 1) & 1) * 32768 + (wc >> 1) * 16384 + (wc & 1) * 8192;
      loadR1(bA1, bB1);
    }
  }

  // epilogue
#pragma unroll
  for (int m = 0; m < 8; ++m)
#pragma unroll
    for (int n = 0; n < 4; ++n) {
      size_t row = rowBase + wr * 128 + m * 16 + g * 4;
      size_t col = colBase + wc * 64 + n * 16 + c;
#pragma unroll
      for (int r = 0; r < 4; ++r)
        storeC(&C[(row + r) * (size_t)N + col], acc[m][n][r]);
    }
}

// ---------------- RoPE on q,k; writes Q,K in [B,H,S,HD] --------------------
__global__ void rope_qk(const u16* __restrict__ qkv, const float* __restrict__ tab,
                        u16* __restrict__ Q, u16* __restrict__ K) {
  int idx = blockIdx.x * 256 + threadIdx.x;
  int j = idx & 63;
  int s = (idx >> 6) & (S_LEN - 1);
  int h = (idx >> 17) & (NH - 1);
  int b = idx >> 21;
  float cs = tab[s * 64 + j];
  float sn = tab[131072 + s * 64 + j];
  size_t qbase = (((size_t)(b * S_LEN + s) * 3 + 0) * NH + h) * HD;
  size_t kbase = qbase + (size_t)NH * HD;
  size_t o = ((size_t)(b * NH + h) * S_LEN + s) * HD;
  float q1 = bf2f(qkv[qbase + j]),  q2 = bf2f(qkv[qbase + j + 64]);
  Q[o + j]      = f2bf(q1 * cs - q2 * sn);
  Q[o + j + 64] = f2bf(q2 * cs + q1 * sn);
  float k1 = bf2f(qkv[kbase + j]), k2 = bf2f(qkv[kbase + j + 64]);
  K[o + j]      = f2bf(k1 * cs - k2 * sn);
  K[o + j + 64] = f2bf(k2 * cs + k1 * sn);
}

// ---------------- V transpose: qkv v-slot -> Vt [B,H,HD,S] -----------------
__global__ void v_transpose(const u16* __restrict__ qkv, u16* __restrict__ Vt) {
  __shared__ u16 t[32][33];
  int bh = blockIdx.z;
  int s0 = blockIdx.x * 32;
  int d0 = blockIdx.y * 32;
  int b = bh >> 4, h = bh & 15;
  int col = threadIdx.x & 31;
  int row = threadIdx.x >> 5;
#pragma unroll
  for (int i = 0; i < 4; ++i) {
    int s = row + i * 8;
    t[s][col] = qkv[(((size_t)(b * S_LEN + s0 + s) * 3 + 2) * NH + h) * HD + d0 + col];
  }
  __syncthreads();
  size_t vb = ((size_t)bh * HD + d0) * S_LEN + s0;
#pragma unroll
  for (int i = 0; i < 4; ++i) {
    int d = row + i * 8;
    Vt[vb + (size_t)d * S_LEN + col] = t[col][d];
  }
}

// ---------------- causal flash attention: 8-wave block, LDS-staged K/V -----
__global__ __launch_bounds__(512, 4) void attn_fwd(const u16* __restrict__ Q, const u16* __restrict__ K,
                                                   const u16* __restrict__ Vt, u16* __restrict__ O) {
  __shared__ alignas(16) u16 Ks[2 * 64 * 128];
  __shared__ alignas(16) u16 Vs[2 * 128 * 64];
  __shared__ alignas(16) u16 Pl[8 * 16 * 64];
  const int tid = threadIdx.x;
  const int lane = tid & 63;
  const int w = tid >> 6;
  const int g = lane >> 4, c = lane & 15;
  const int bh = blockIdx.x;
  const int pair = blockIdx.y;
  const int b = bh >> 4, h = bh & 15;

  const u16* Qb = Q + (size_t)bh * S_LEN * HD;
  const u16* Kb = K + (size_t)bh * S_LEN * HD;
  const u16* Vb = Vt + (size_t)bh * HD * S_LEN;
  const float SL = 0.12751753f;
  const int swz = (c & 7) << 4;

  int ldsOff[2], srcK[2], srcV[2];
#pragma unroll
  for (int ii = 0; ii < 2; ++ii) {
    int p = (w * 2 + ii) * 1024 + lane * 16;
    ldsOff[ii] = p;
    int rk = p >> 8, ik = p & 255;
    srcK[ii] = rk * 256 + (ik ^ ((rk & 7) << 4));
    int rv = p >> 7, iv = p & 127;
    srcV[ii] = rv * (S_LEN * 2) + (iv ^ ((rv & 7) << 4));
  }
  int koff[4], voff[2];
#pragma unroll
  for (int kb = 0; kb < 4; ++kb) koff[kb] = (kb * 64 + g * 16) ^ swz;
  voff[0] = (g * 16) ^ swz;
  voff[1] = (64 + g * 16) ^ swz;
  int poff[4];
#pragma unroll
  for (int t = 0; t < 4; ++t) poff[t] = (t * 32 + g * 8) ^ swz;
  char* Pw = (char*)Pl + w * 2048;

#pragma unroll 1
  for (int ph = 0; ph < 2; ++ph) {
    const int sti = ph ? (15 - pair) : pair;
    const int qb0 = sti * 128;
    const int q0 = qb0 + w * 16;

    bf16x8 qf[4];
#pragma unroll
    for (int kb = 0; kb < 4; ++kb)
      qf[kb] = *(const bf16x8*)&Qb[(size_t)(q0 + c) * HD + kb * 32 + g * 8];

    f32x4 acc[8];
#pragma unroll
    for (int cb = 0; cb < 8; ++cb) acc[cb] = f32x4{0.f, 0.f, 0.f, 0.f};
    float m_i = -3e38f, l_i = 0.f;

    const int nsteps = sti * 2 + 2;
#pragma unroll
    for (int ii = 0; ii < 2; ++ii) {
      __builtin_amdgcn_global_load_lds((const AS1 void*)((const char*)Kb + srcK[ii]),
                                       (AS3 void*)((char*)Ks + ldsOff[ii] - lane * 16), 16, 0, 0);
      __builtin_amdgcn_global_load_lds((const AS1 void*)((const char*)Vb + srcV[ii]),
                                       (AS3 void*)((char*)Vs + ldsOff[ii] - lane * 16), 16, 0, 0);
    }
    __syncthreads();
    int cur = 0;

#pragma unroll 1
    for (int st = 0; st < nsteps; ++st) {
      const int kv0 = st << 6;
      if (st + 1 < nsteps) {
        const char* kbase = (const char*)Kb + (size_t)(kv0 + 64) * 256;
        const char* vbase = (const char*)Vb + (size_t)(kv0 + 64) * 2;
        const int nb = (cur ^ 1) * 16384;
#pragma unroll
        for (int ii = 0; ii < 2; ++ii) {
          __builtin_amdgcn_global_load_lds((const AS1 void*)(kbase + srcK[ii]),
                                           (AS3 void*)((char*)Ks + nb + ldsOff[ii] - lane * 16), 16, 0, 0);
          __builtin_amdgcn_global_load_lds((const AS1 void*)(vbase + srcV[ii]),
                                           (AS3 void*)((char*)Vs + nb + ldsOff[ii] - lane * 16), 16, 0, 0);
        }
      }
      if (kv0 < q0 + 16) {
        const char* Kt = (const char*)Ks + cur * 16384;
        const char* Vtl = (const char*)Vs + cur * 16384;
        f32x4 s[4];
#pragma unroll
        for (int t = 0; t < 4; ++t) s[t] = f32x4{0.f, 0.f, 0.f, 0.f};
#pragma unroll
        for (int t = 0; t < 4; ++t)
#pragma unroll
          for (int kb = 0; kb < 4; ++kb) {
            bf16x8 kf = *(const bf16x8*)(Kt + t * 4096 + c * 256 + koff[kb]);
            s[t] = __builtin_amdgcn_mfma_f32_16x16x32_bf16(kf, qf[kb], s[t], 0, 0, 0);
          }
        if (kv0 + 63 > q0) {
          const int lim = q0 + c - kv0 - 4 * g;
#pragma unroll
          for (int t = 0; t < 4; ++t)
#pragma unroll
            for (int r = 0; r < 4; ++r)
              s[t][r] = (16 * t + r <= lim) ? s[t][r] : -3e38f;
        }
        float mx = s[0][0];
#pragma unroll
        for (int t = 0; t < 4; ++t)
#pragma unroll
          for (int r = 0; r < 4; ++r) mx = fmaxf(mx, s[t][r]);
        mx = fmaxf(mx, __shfl_xor(mx, 16));
        mx = fmaxf(mx, __shfl_xor(mx, 32));
        const float mn = fmaxf(m_i, mx);
        const float alpha = exp2f((m_i - mn) * SL);
        float rs = 0.f;
#pragma unroll
        for (int t = 0; t < 4; ++t) {
          float p0 = exp2f((s[t][0] - mn) * SL);
          float p1 = exp2f((s[t][1] - mn) * SL);
          float p2 = exp2f((s[t][2] - mn) * SL);
          float p3 = exp2f((s[t][3] - mn) * SL);
          rs += (p0 + p1) + (p2 + p3);
          ushort4 pw;
          pw.x = f2bf(p0); pw.y = f2bf(p1); pw.z = f2bf(p2); pw.w = f2bf(p3);
          *(ushort4*)(Pw + c * 128 + poff[t]) = pw;
        }
        rs += __shfl_xor(rs, 16);
        rs += __shfl_xor(rs, 32);
        l_i = l_i * alpha + rs;
        m_i = mn;
        float ar[4];
#pragma unroll
        for (int r = 0; r < 4; ++r) ar[r] = __shfl(alpha, 4 * g + r);
#pragma unroll
        for (int cb = 0; cb < 8; ++cb)
#pragma unroll
          for (int r = 0; r < 4; ++r) acc[cb][r] *= ar[r];
        bf16x8 pa0 = *(const bf16x8*)(Pw + c * 128 + voff[0]);
        bf16x8 pa1 = *(const bf16x8*)(Pw + c * 128 + voff[1]);
#pragma unroll
        for (int cb = 0; cb < 8; ++cb) {
          bf16x8 vf0 = *(const bf16x8*)(Vtl + cb * 2048 + c * 128 + voff[0]);
          acc[cb] = __builtin_amdgcn_mfma_f32_16x16x32_bf16(pa0, vf0, acc[cb], 0, 0, 0);
          bf16x8 vf1 = *(const bf16x8*)(Vtl + cb * 2048 + c * 128 + voff[1]);
          acc[cb] = __builtin_amdgcn_mfma_f32_16x16x32_bf16(pa1, vf1, acc[cb], 0, 0, 0);
        }
      }
      __syncthreads();
      cur ^= 1;
    }
    float linv = 1.0f / l_i;
    float lr[4];
#pragma unroll
    for (int r = 0; r < 4; ++r) lr[r] = __shfl(linv, 4 * g + r);
#pragma unroll
    for (int cb = 0; cb < 8; ++cb)
#pragma unroll
      for (int r = 0; r < 4; ++r) {
        int q = q0 + 4 * g + r;
        O[(((size_t)b * S_LEN + q) * NH + h) * HD + cb * 16 + c] = f2bf(acc[cb][r] * lr[r]);
      }
  }
}

// ---------------------------------------------------------------------------
extern "C" void kernel_launch(void* const* d_in, const int* in_sizes, int n_in,
                              void* d_out, int out_size, void* d_ws, size_t ws_size,
                              hipStream_t stream) {
  const float* x    = (const float*)d_in[0];
  const float* wqkv = (const float*)d_in[1];
  const float* wo   = (const float*)d_in[2];
  float* out = (float*)d_out;
  char* ws = (char*)d_ws;

  u16*  xb    = (u16*)(ws + 0);            // reused as attn out later
  u16*  wqkvb = (u16*)(ws + 33554432);
  float* tab  = (float*)(ws + 58720256);   // unioned with wob (tab dead after rope)
  u16*  wob   = (u16*)(ws + 58720256);
  u16*  qkvb  = (u16*)(ws + 67108864);
  u16*  Vt    = (u16*)(ws + 167772160);
  u16*  attn  = (u16*)(ws + 0);
  u16*  Qr = (u16*)d_out;                  // d_out scratch: dead before GEMM2
  u16*  Kr = (u16*)d_out + 16777216;

  cvt_f32_bf16<<<16384, 256, 0, stream>>>(x, xb, 16777216 / 4);
  cvt_f32_bf16<<<12288, 256, 0, stream>>>(wqkv, wqkvb, 12582912 / 4);
  build_tab<<<512, 256, 0, stream>>>(tab);

  // qkv = x @ wqkv^T : M=8192, N=6144, K=2048 -> 24x32 = 768 blocks
  gemm_bt6<u16><<<768, 512, 0, stream>>>(xb, wqkvb, qkvb, 8192, 6144, 2048, 24);

  rope_qk<<<32768, 256, 0, stream>>>(qkvb, tab, Qr, Kr);
  v_transpose<<<dim3(64, 4, 64), 256, 0, stream>>>(qkvb, Vt);

  cvt_f32_bf16<<<4096, 256, 0, stream>>>(wo, wob, 4194304 / 4);

  attn_fwd<<<dim3(64, 8), 512, 0, stream>>>(Qr, Kr, Vt, attn);

  // out = attn @ wo^T : M=8192, N=2048, K=2048 -> 8x32 = 256 blocks
  gemm_bt6<float><<<256, 512, 0, stream>>>(attn, wob, out, 8192, 2048, 2048, 8);
}